// Round 1
// baseline (1811.933 us; speedup 1.0000x reference)
//
#include <hip/hip_runtime.h>

#define B_ 256
#define S_ 80
#define H_ 512
#define WD_ 1024
#define V_ 4096
#define NSTEP 27

// monotonic key for f32 (order-preserving as unsigned)
__device__ __forceinline__ unsigned fkey(float v){
    unsigned u = __float_as_uint(v);
    return (u & 0x80000000u) ? ~u : (u | 0x80000000u);
}

// out[row] = dot(W[row, 0:512], v)   (row length/ld = 512)
__global__ __launch_bounds__(64) void matvec512(const float* __restrict__ W,
                                                const float* __restrict__ v,
                                                float* __restrict__ out){
    int row = blockIdx.x;
    int lane = threadIdx.x;
    const float* wr = W + row * 512;
    float s = 0.f;
#pragma unroll
    for (int i = 0; i < 8; ++i) s += wr[lane + 64*i] * v[lane + 64*i];
#pragma unroll
    for (int off = 32; off; off >>= 1) s += __shfl_xor(s, off);
    if (lane == 0) out[row] = s;
}

// scores[p] = dot(enc[p*512 ...], weff)  for p = (b*80+s)
__global__ __launch_bounds__(256) void score_kernel(const float* __restrict__ enc,
                                                    const float* __restrict__ weff,
                                                    float* __restrict__ scores){
    int wv = threadIdx.x >> 6, lane = threadIdx.x & 63;
    int p = blockIdx.x * 4 + wv;
    const float* e = enc + (size_t)p * 512;
    float s = 0.f;
#pragma unroll
    for (int i = 0; i < 8; ++i) s += e[lane + 64*i] * weff[lane + 64*i];
#pragma unroll
    for (int off = 32; off; off >>= 1) s += __shfl_xor(s, off);
    if (lane == 0) scores[p] = s;
}

// per-b softmax over S=80 then ctx[b,k] = sum_s attw[s]*enc[b,s,k]
__global__ __launch_bounds__(512) void softmax_ctx(const float* __restrict__ enc,
                                                   const float* __restrict__ scores,
                                                   float* __restrict__ ctx){
    __shared__ float att[S_];
    int b = blockIdx.x, tid = threadIdx.x;
    if (tid < S_) att[tid] = scores[b*S_ + tid];
    __syncthreads();
    if (tid == 0){
        float mx = att[0];
        for (int s = 1; s < S_; ++s) mx = fmaxf(mx, att[s]);
        float sum = 0.f;
        for (int s = 0; s < S_; ++s){ float e = expf(att[s] - mx); att[s] = e; sum += e; }
        float inv = 1.f / sum;
        for (int s = 0; s < S_; ++s) att[s] *= inv;
    }
    __syncthreads();
    float a = 0.f;
    const float* eb = enc + (size_t)b * (S_*H_);
    for (int s = 0; s < S_; ++s) a += att[s] * eb[s*H_ + tid];
    ctx[b*H_ + tid] = a;
}

// C[m,n] = sum_k A[m*lda+k]*Bm[n*ldb+k] (+ bias[n]).  Tile TM x 64, BK=16, 256 thr.
template<int TM>
__global__ __launch_bounds__(256) void gemm_abt(const float* __restrict__ A, int lda,
                                                const float* __restrict__ Bm, int ldb,
                                                const float* __restrict__ bias,
                                                float* __restrict__ C, int ldc,
                                                int K){
    constexpr int RPT = TM / 16;
    __shared__ float As[16][TM + 4];
    __shared__ float Bs[16][64 + 4];
    int m0 = blockIdx.x * TM, n0 = blockIdx.y * 64;
    int tid = threadIdx.x;
    int lk = tid & 15, lr = tid >> 4;
    int tx = tid & 15, ty = tid >> 4;
    float c[RPT][4] = {};
    for (int k0 = 0; k0 < K; k0 += 16){
#pragma unroll
        for (int i = 0; i < RPT; ++i)
            As[lk][lr*RPT + i] = A[(size_t)(m0 + lr*RPT + i)*lda + k0 + lk];
#pragma unroll
        for (int i = 0; i < 4; ++i)
            Bs[lk][lr*4 + i] = Bm[(size_t)(n0 + lr*4 + i)*ldb + k0 + lk];
        __syncthreads();
#pragma unroll
        for (int k = 0; k < 16; ++k){
            float b4[4];
            *(float4*)b4 = *(const float4*)&Bs[k][tx*4];
#pragma unroll
            for (int i = 0; i < RPT; ++i){
                float a = As[k][ty*RPT + i];
#pragma unroll
                for (int j = 0; j < 4; ++j) c[i][j] += a * b4[j];
            }
        }
        __syncthreads();
    }
#pragma unroll
    for (int j = 0; j < 4; ++j){
        float bb = bias ? bias[n0 + tx*4 + j] : 0.f;
#pragma unroll
        for (int i = 0; i < RPT; ++i)
            C[(size_t)(m0 + ty*RPT + i)*ldc + n0 + tx*4 + j] = c[i][j] + bb;
    }
}

// One decode step, hidden part: gh = h@W_hh^T (fused over 3 gates) + GRU pointwise.
// Also: decodes prev argmax (w), writes preds[:, t-1], zeroes Pcur for this step's logits.
// grid (8, 32): 32-row tile x 16 gate-j (x3 gates). 256 thr.
__global__ __launch_bounds__(256) void step_hidden(const float* __restrict__ h_in,
                                                   float* __restrict__ h_out,
                                                   const float* __restrict__ Whh,
                                                   const float* __restrict__ bhh,
                                                   const float* __restrict__ Eproj,
                                                   const float* __restrict__ gictx,
                                                   const unsigned long long* __restrict__ Pprev,
                                                   unsigned long long* __restrict__ Pzero,
                                                   float* __restrict__ preds, int t){
    __shared__ float Hs[16][32 + 4];
    __shared__ float Ws[16][48 + 4];
    __shared__ int widx[32];
    int m0 = blockIdx.x * 32, j0 = blockIdx.y * 16;
    int tid = threadIdx.x;
    if (blockIdx.x == 0 && blockIdx.y == 0) Pzero[tid] = 0ULL;  // 256 entries
    if (tid < 32){
        int b = m0 + tid;
        int w = 1;
        if (t > 0){
            w = 4095 - (int)(Pprev[b] & 0xFFFFFFFFull);
            if (w < 0) w = 0; if (w > 4095) w = 4095;
            if (blockIdx.y == 0) preds[b*NSTEP + (t-1)] = (float)w;
        }
        widx[tid] = w;
    }
    int lk = tid & 15, lr = tid >> 4;
    int jj = tid & 15, rq = tid >> 4;
    float acc[2][3] = {};
    for (int k0 = 0; k0 < 512; k0 += 16){
#pragma unroll
        for (int i = 0; i < 2; ++i)
            Hs[lk][lr*2 + i] = h_in[(size_t)(m0 + lr*2 + i)*512 + k0 + lk];
#pragma unroll
        for (int g = 0; g < 3; ++g)
            Ws[lk][lr + 16*g] = Whh[(size_t)(g*512 + j0 + lr)*512 + k0 + lk];
        __syncthreads();
#pragma unroll
        for (int k = 0; k < 16; ++k){
            float w0 = Ws[k][jj], w1 = Ws[k][jj + 16], w2 = Ws[k][jj + 32];
#pragma unroll
            for (int i = 0; i < 2; ++i){
                float a = Hs[k][rq*2 + i];
                acc[i][0] += a * w0; acc[i][1] += a * w1; acc[i][2] += a * w2;
            }
        }
        __syncthreads();
    }
    int j = j0 + jj;
    float br = bhh[j], bz = bhh[512 + j], bn = bhh[1024 + j];
#pragma unroll
    for (int i = 0; i < 2; ++i){
        int rloc = rq*2 + i;
        int b = m0 + rloc;
        int w = widx[rloc];
        const float* ep = Eproj + (size_t)w * 1536;
        const float* gc = gictx + (size_t)b * 1536;
        float gir = ep[j]        + gc[j];
        float giz = ep[512 + j]  + gc[512 + j];
        float gin = ep[1024 + j] + gc[1024 + j];
        float r = 1.f / (1.f + expf(-(gir + acc[i][0] + br)));
        float z = 1.f / (1.f + expf(-(giz + acc[i][1] + bz)));
        float n = tanhf(gin + r * (acc[i][2] + bn));
        float hold = h_in[(size_t)b*512 + j];
        h_out[(size_t)b*512 + j] = (1.f - z)*n + z*hold;
    }
}

// logits = hn @ Wo + bo -> d_out slice; fused argmax via packed u64 atomicMax.
// grid (8, 64): 32-row x 64-col tiles. 256 thr. B is (K=512, N=4096) row-major.
__global__ __launch_bounds__(256) void gemm_logits(const float* __restrict__ A,
                                                   const float* __restrict__ Bw,
                                                   const float* __restrict__ bias,
                                                   float* __restrict__ Cout,
                                                   unsigned long long* __restrict__ Pcur){
    __shared__ float As[16][32 + 4];
    __shared__ float Bs[16][64 + 4];
    int m0 = blockIdx.x * 32, n0 = blockIdx.y * 64;
    int tid = threadIdx.x;
    int lk = tid & 15, lr = tid >> 4;
    int ln = tid & 63, lkk = tid >> 6;
    int tx = tid & 15, ty = tid >> 4;
    float c[2][4] = {};
    for (int k0 = 0; k0 < 512; k0 += 16){
#pragma unroll
        for (int i = 0; i < 2; ++i)
            As[lk][lr*2 + i] = A[(size_t)(m0 + lr*2 + i)*512 + k0 + lk];
#pragma unroll
        for (int i = 0; i < 4; ++i)
            Bs[lkk*4 + i][ln] = Bw[(size_t)(k0 + lkk*4 + i)*4096 + n0 + ln];
        __syncthreads();
#pragma unroll
        for (int k = 0; k < 16; ++k){
            float b4[4];
            *(float4*)b4 = *(const float4*)&Bs[k][tx*4];
#pragma unroll
            for (int i = 0; i < 2; ++i){
                float a = As[k][ty*2 + i];
                c[i][0] += a*b4[0]; c[i][1] += a*b4[1]; c[i][2] += a*b4[2]; c[i][3] += a*b4[3];
            }
        }
        __syncthreads();
    }
#pragma unroll
    for (int i = 0; i < 2; ++i){
        int row = m0 + ty*2 + i;
        float* crow = Cout + (size_t)row * (NSTEP * (size_t)V_);
        unsigned long long best = 0ULL;
#pragma unroll
        for (int j = 0; j < 4; ++j){
            int v = n0 + tx*4 + j;
            float val = c[i][j] + bias[v];
            crow[v] = val;
            unsigned long long pk = ((unsigned long long)fkey(val) << 32) | (unsigned)(4095 - v);
            if (pk > best) best = pk;
        }
#pragma unroll
        for (int off = 1; off < 16; off <<= 1){
            unsigned long long o = __shfl_xor(best, off);
            if (o > best) best = o;
        }
        if (tx == 0) atomicMax(&Pcur[row], best);
    }
}

__global__ __launch_bounds__(256) void final_pred(const unsigned long long* __restrict__ P,
                                                  float* __restrict__ preds){
    int b = threadIdx.x;
    int w = 4095 - (int)(P[b] & 0xFFFFFFFFull);
    if (w < 0) w = 0; if (w > 4095) w = 4095;
    preds[b*NSTEP + (NSTEP-1)] = (float)w;
}

extern "C" void kernel_launch(void* const* d_in, const int* in_sizes, int n_in,
                              void* d_out, int out_size, void* d_ws, size_t ws_size,
                              hipStream_t stream){
    const float* elhs = (const float*)d_in[0];   // (1,256,512)
    const float* enc  = (const float*)d_in[1];   // (256,80,512)
    const float* emb  = (const float*)d_in[3];   // (4096,1024)
    const float* W1   = (const float*)d_in[4];   // (1024,512)
    const float* W2   = (const float*)d_in[6];   // (512,512)
    const float* W3   = (const float*)d_in[8];
    const float* W4   = (const float*)d_in[10];
    const float* Ww   = (const float*)d_in[12];  // (512,1)
    const float* Wih  = (const float*)d_in[13];  // (1536,1536)
    const float* bih  = (const float*)d_in[14];
    const float* Whh  = (const float*)d_in[15];  // (1536,512)
    const float* bhh  = (const float*)d_in[16];
    const float* Wo   = (const float*)d_in[17];  // (512,4096)
    const float* bo   = (const float*)d_in[18];

    float* out = (float*)d_out;
    float* preds = out + (size_t)B_ * NSTEP * V_;

    float* ws = (float*)d_ws;
    float* Eproj  = ws;  ws += (size_t)V_ * 1536;   // 6291456
    float* gictx  = ws;  ws += (size_t)B_ * 1536;   // 393216
    float* ctx    = ws;  ws += B_ * H_;             // 131072
    float* scores = ws;  ws += B_ * S_;             // 20480
    float* t1     = ws;  ws += 512;
    float* t2     = ws;  ws += 512;
    float* weff   = ws;  ws += 512;
    float* Hbuf0  = ws;  ws += B_ * H_;
    float* Hbuf1  = ws;  ws += B_ * H_;
    unsigned long long* P = (unsigned long long*)ws;  // 2*256 entries

    // collapse attention MLP: weff = (W1@W2@W3@W4@Ww)[0:512]
    matvec512<<<512, 64, 0, stream>>>(W4, Ww, t1);
    matvec512<<<512, 64, 0, stream>>>(W3, t1, t2);
    matvec512<<<512, 64, 0, stream>>>(W2, t2, t1);
    matvec512<<<512, 64, 0, stream>>>(W1, t1, weff);
    // scores + softmax + context (h-independent => once)
    score_kernel<<<(B_*S_)/4, 256, 0, stream>>>(enc, weff, scores);
    softmax_ctx<<<B_, 512, 0, stream>>>(enc, scores, ctx);
    // gi_ctx = ctx @ W_ih[:,1024:]^T + b_ih   (256x1536, K=512)
    {
        dim3 g(B_/32, 1536/64);
        gemm_abt<32><<<g, 256, 0, stream>>>(ctx, 512, Wih + 1024, 1536, bih, gictx, 1536, 512);
    }
    // E_proj = embedding @ W_ih[:,0:1024]^T   (4096x1536, K=1024)
    {
        dim3 g(V_/64, 1536/64);
        gemm_abt<64><<<g, 256, 0, stream>>>(emb, 1024, Wih, 1536, nullptr, Eproj, 1536, 1024);
    }

    for (int t = 0; t < NSTEP; ++t){
        const float* hin = (t == 0) ? elhs : ((t & 1) ? Hbuf0 : Hbuf1);
        float* hout = (t & 1) ? Hbuf1 : Hbuf0;
        const unsigned long long* Pprev = (t == 0) ? nullptr : P + ((t-1) & 1) * B_;
        unsigned long long* Pcur = P + (t & 1) * B_;
        dim3 gs(B_/32, 512/16);
        step_hidden<<<gs, 256, 0, stream>>>(hin, hout, Whh, bhh, Eproj, gictx, Pprev, Pcur, preds, t);
        dim3 gl(B_/32, V_/64);
        gemm_logits<<<gl, 256, 0, stream>>>(hout, Wo, bo, out + (size_t)t * V_, Pcur);
    }
    final_pred<<<1, 256, 0, stream>>>(P, preds);  // step 26 parity: P[0]
}

// Round 2
// 1655.353 us; speedup vs baseline: 1.0946x; 1.0946x over previous
//
#include <hip/hip_runtime.h>

#define B_ 256
#define S_ 80
#define H_ 512
#define WD_ 1024
#define V_ 4096
#define NSTEP 27

typedef __attribute__((ext_vector_type(8))) short short8v;
typedef __attribute__((ext_vector_type(4))) float f32x4;

// monotonic key for f32 (order-preserving as unsigned)
__device__ __forceinline__ unsigned fkey(float v){
    unsigned u = __float_as_uint(v);
    return (u & 0x80000000u) ? ~u : (u | 0x80000000u);
}

__device__ __forceinline__ unsigned short bf16_rne(float f){
    unsigned u = __float_as_uint(f);
    unsigned r = (u + 0x7FFFu + ((u >> 16) & 1u)) >> 16;
    return (unsigned short)r;
}

// out[row] = dot(W[row, 0:512], v)
__global__ __launch_bounds__(64) void matvec512(const float* __restrict__ W,
                                                const float* __restrict__ v,
                                                float* __restrict__ out){
    int row = blockIdx.x;
    int lane = threadIdx.x;
    const float* wr = W + row * 512;
    float s = 0.f;
#pragma unroll
    for (int i = 0; i < 8; ++i) s += wr[lane + 64*i] * v[lane + 64*i];
#pragma unroll
    for (int off = 32; off; off >>= 1) s += __shfl_xor(s, off);
    if (lane == 0) out[row] = s;
}

__global__ __launch_bounds__(256) void score_kernel(const float* __restrict__ enc,
                                                    const float* __restrict__ weff,
                                                    float* __restrict__ scores){
    int wv = threadIdx.x >> 6, lane = threadIdx.x & 63;
    int p = blockIdx.x * 4 + wv;
    const float* e = enc + (size_t)p * 512;
    float s = 0.f;
#pragma unroll
    for (int i = 0; i < 8; ++i) s += e[lane + 64*i] * weff[lane + 64*i];
#pragma unroll
    for (int off = 32; off; off >>= 1) s += __shfl_xor(s, off);
    if (lane == 0) scores[p] = s;
}

__global__ __launch_bounds__(512) void softmax_ctx(const float* __restrict__ enc,
                                                   const float* __restrict__ scores,
                                                   float* __restrict__ ctx){
    __shared__ float att[S_];
    int b = blockIdx.x, tid = threadIdx.x;
    if (tid < S_) att[tid] = scores[b*S_ + tid];
    __syncthreads();
    if (tid == 0){
        float mx = att[0];
        for (int s = 1; s < S_; ++s) mx = fmaxf(mx, att[s]);
        float sum = 0.f;
        for (int s = 0; s < S_; ++s){ float e = expf(att[s] - mx); att[s] = e; sum += e; }
        float inv = 1.f / sum;
        for (int s = 0; s < S_; ++s) att[s] *= inv;
    }
    __syncthreads();
    float a = 0.f;
    const float* eb = enc + (size_t)b * (S_*H_);
    for (int s = 0; s < S_; ++s) a += att[s] * eb[s*H_ + tid];
    ctx[b*H_ + tid] = a;
}

// small f32 GEMM (kept for gictx): C[m,n] = sum_k A[m,k]*Bm[n,k] + bias
template<int TM>
__global__ __launch_bounds__(256) void gemm_abt(const float* __restrict__ A, int lda,
                                                const float* __restrict__ Bm, int ldb,
                                                const float* __restrict__ bias,
                                                float* __restrict__ C, int ldc,
                                                int K){
    constexpr int RPT = TM / 16;
    __shared__ float As[16][TM + 4];
    __shared__ float Bs[16][64 + 4];
    int m0 = blockIdx.x * TM, n0 = blockIdx.y * 64;
    int tid = threadIdx.x;
    int lk = tid & 15, lr = tid >> 4;
    int tx = tid & 15, ty = tid >> 4;
    float c[RPT][4] = {};
    for (int k0 = 0; k0 < K; k0 += 16){
#pragma unroll
        for (int i = 0; i < RPT; ++i)
            As[lk][lr*RPT + i] = A[(size_t)(m0 + lr*RPT + i)*lda + k0 + lk];
#pragma unroll
        for (int i = 0; i < 4; ++i)
            Bs[lk][lr*4 + i] = Bm[(size_t)(n0 + lr*4 + i)*ldb + k0 + lk];
        __syncthreads();
#pragma unroll
        for (int k = 0; k < 16; ++k){
            float b4[4];
            *(float4*)b4 = *(const float4*)&Bs[k][tx*4];
#pragma unroll
            for (int i = 0; i < RPT; ++i){
                float a = As[k][ty*RPT + i];
#pragma unroll
                for (int j = 0; j < 4; ++j) c[i][j] += a * b4[j];
            }
        }
        __syncthreads();
    }
#pragma unroll
    for (int j = 0; j < 4; ++j){
        float bb = bias ? bias[n0 + tx*4 + j] : 0.f;
#pragma unroll
        for (int i = 0; i < RPT; ++i)
            C[(size_t)(m0 + ty*RPT + i)*ldc + n0 + tx*4 + j] = c[i][j] + bb;
    }
}

// f32 GEMM, 128x128 tile, c[8][8]/thread (VALU-bound): for Eproj
__global__ __launch_bounds__(256) void gemm128(const float* __restrict__ A, int lda,
                                               const float* __restrict__ Bm, int ldb,
                                               float* __restrict__ C, int ldc, int K){
    __shared__ float As[16][132];
    __shared__ float Bs[16][132];
    int m0 = blockIdx.x * 128, n0 = blockIdx.y * 128;
    int tid = threadIdx.x;
    int sm = tid & 127;
    int sh = (tid >> 7) * 8;
    int tx = tid & 15, ty = tid >> 4;
    float4 a0 = *(const float4*)&A[(size_t)(m0+sm)*lda + sh];
    float4 a1 = *(const float4*)&A[(size_t)(m0+sm)*lda + sh + 4];
    float4 b0 = *(const float4*)&Bm[(size_t)(n0+sm)*ldb + sh];
    float4 b1 = *(const float4*)&Bm[(size_t)(n0+sm)*ldb + sh + 4];
    float c[8][8] = {};
    for (int k0 = 0; k0 < K; k0 += 16){
        __syncthreads();
        As[sh+0][sm]=a0.x; As[sh+1][sm]=a0.y; As[sh+2][sm]=a0.z; As[sh+3][sm]=a0.w;
        As[sh+4][sm]=a1.x; As[sh+5][sm]=a1.y; As[sh+6][sm]=a1.z; As[sh+7][sm]=a1.w;
        Bs[sh+0][sm]=b0.x; Bs[sh+1][sm]=b0.y; Bs[sh+2][sm]=b0.z; Bs[sh+3][sm]=b0.w;
        Bs[sh+4][sm]=b1.x; Bs[sh+5][sm]=b1.y; Bs[sh+6][sm]=b1.z; Bs[sh+7][sm]=b1.w;
        __syncthreads();
        if (k0 + 16 < K){
            a0 = *(const float4*)&A[(size_t)(m0+sm)*lda + k0+16 + sh];
            a1 = *(const float4*)&A[(size_t)(m0+sm)*lda + k0+16 + sh + 4];
            b0 = *(const float4*)&Bm[(size_t)(n0+sm)*ldb + k0+16 + sh];
            b1 = *(const float4*)&Bm[(size_t)(n0+sm)*ldb + k0+16 + sh + 4];
        }
#pragma unroll
        for (int k = 0; k < 16; ++k){
            float a[8], b[8];
            *(float4*)&a[0] = *(const float4*)&As[k][ty*8];
            *(float4*)&a[4] = *(const float4*)&As[k][ty*8 + 4];
            *(float4*)&b[0] = *(const float4*)&Bs[k][tx*8];
            *(float4*)&b[4] = *(const float4*)&Bs[k][tx*8 + 4];
#pragma unroll
            for (int i = 0; i < 8; ++i)
#pragma unroll
                for (int j = 0; j < 8; ++j) c[i][j] += a[i] * b[j];
        }
    }
#pragma unroll
    for (int i = 0; i < 8; ++i){
        float* cr = &C[(size_t)(m0 + ty*8 + i)*ldc + n0 + tx*8];
        float4 v0 = make_float4(c[i][0], c[i][1], c[i][2], c[i][3]);
        float4 v1 = make_float4(c[i][4], c[i][5], c[i][6], c[i][7]);
        *(float4*)&cr[0] = v0;
        *(float4*)&cr[4] = v1;
    }
}

// Wo (512x4096, k-major) -> transposed bf16 splits WoT_hi/lo (4096x512, n-major)
__global__ __launch_bounds__(256) void wo_split(const float* __restrict__ Wo,
                                                unsigned short* __restrict__ Thi,
                                                unsigned short* __restrict__ Tlo){
    __shared__ float T[64][65];
    int k0 = blockIdx.x * 64, n0 = blockIdx.y * 64;
    int tid = threadIdx.x;
#pragma unroll
    for (int i = 0; i < 16; ++i){
        int idx = tid + i*256;
        int kk = idx >> 6, nn = idx & 63;
        T[kk][nn] = Wo[(size_t)(k0+kk)*4096 + n0+nn];
    }
    __syncthreads();
#pragma unroll
    for (int i = 0; i < 16; ++i){
        int idx = tid + i*256;
        int nn = idx >> 6, kk = idx & 63;
        float v = T[kk][nn];
        unsigned short hi = bf16_rne(v);
        float hf = __uint_as_float(((unsigned)hi) << 16);
        unsigned short lo = bf16_rne(v - hf);
        size_t o = (size_t)(n0+nn)*512 + k0+kk;
        Thi[o] = hi; Tlo[o] = lo;
    }
}

// One decode step hidden part (unchanged core) + writes bf16 splits of hn
__global__ __launch_bounds__(256) void step_hidden(const float* __restrict__ h_in,
                                                   float* __restrict__ h_out,
                                                   unsigned short* __restrict__ hn_hi,
                                                   unsigned short* __restrict__ hn_lo,
                                                   const float* __restrict__ Whh,
                                                   const float* __restrict__ bhh,
                                                   const float* __restrict__ Eproj,
                                                   const float* __restrict__ gictx,
                                                   const unsigned long long* __restrict__ Pprev,
                                                   unsigned long long* __restrict__ Pzero,
                                                   float* __restrict__ preds, int t){
    __shared__ float Hs[16][32 + 4];
    __shared__ float Ws[16][48 + 4];
    __shared__ int widx[32];
    int m0 = blockIdx.x * 32, j0 = blockIdx.y * 16;
    int tid = threadIdx.x;
    if (blockIdx.x == 0 && blockIdx.y == 0) Pzero[tid] = 0ULL;
    if (tid < 32){
        int b = m0 + tid;
        int w = 1;
        if (t > 0){
            w = 4095 - (int)(Pprev[b] & 0xFFFFFFFFull);
            if (w < 0) w = 0; if (w > 4095) w = 4095;
            if (blockIdx.y == 0) preds[b*NSTEP + (t-1)] = (float)w;
        }
        widx[tid] = w;
    }
    int lk = tid & 15, lr = tid >> 4;
    int jj = tid & 15, rq = tid >> 4;
    float acc[2][3] = {};
    for (int k0 = 0; k0 < 512; k0 += 16){
#pragma unroll
        for (int i = 0; i < 2; ++i)
            Hs[lk][lr*2 + i] = h_in[(size_t)(m0 + lr*2 + i)*512 + k0 + lk];
#pragma unroll
        for (int g = 0; g < 3; ++g)
            Ws[lk][lr + 16*g] = Whh[(size_t)(g*512 + j0 + lr)*512 + k0 + lk];
        __syncthreads();
#pragma unroll
        for (int k = 0; k < 16; ++k){
            float w0 = Ws[k][jj], w1 = Ws[k][jj + 16], w2 = Ws[k][jj + 32];
#pragma unroll
            for (int i = 0; i < 2; ++i){
                float a = Hs[k][rq*2 + i];
                acc[i][0] += a * w0; acc[i][1] += a * w1; acc[i][2] += a * w2;
            }
        }
        __syncthreads();
    }
    int j = j0 + jj;
    float br = bhh[j], bz = bhh[512 + j], bn = bhh[1024 + j];
#pragma unroll
    for (int i = 0; i < 2; ++i){
        int rloc = rq*2 + i;
        int b = m0 + rloc;
        int w = widx[rloc];
        const float* ep = Eproj + (size_t)w * 1536;
        const float* gc = gictx + (size_t)b * 1536;
        float gir = ep[j]        + gc[j];
        float giz = ep[512 + j]  + gc[512 + j];
        float gin = ep[1024 + j] + gc[1024 + j];
        float r = 1.f / (1.f + expf(-(gir + acc[i][0] + br)));
        float z = 1.f / (1.f + expf(-(giz + acc[i][1] + bz)));
        float n = tanhf(gin + r * (acc[i][2] + bn));
        float hold = h_in[(size_t)b*512 + j];
        float val = (1.f - z)*n + z*hold;
        size_t idx = (size_t)b*512 + j;
        h_out[idx] = val;
        unsigned short hb = bf16_rne(val);
        float hf = __uint_as_float(((unsigned)hb) << 16);
        hn_hi[idx] = hb;
        hn_lo[idx] = bf16_rne(val - hf);
    }
}

// logits = hn @ Wo + bo via split-bf16 MFMA (3-product), fused argmax.
// A: hn splits (256x512), B: WoT splits (4096x512 n-major). Tile 64x64, 4 waves 2x2.
__global__ __launch_bounds__(256) void logits_mfma(
    const unsigned short* __restrict__ Ahi, const unsigned short* __restrict__ Alo,
    const unsigned short* __restrict__ Bhi, const unsigned short* __restrict__ Blo,
    const float* __restrict__ bo,
    float* __restrict__ Cout,
    unsigned long long* __restrict__ Pcur){
    __shared__ unsigned short Ah[64][56], Al[64][56], Bh[64][56], Bl[64][56];
    int m0 = blockIdx.x * 64, n0 = blockIdx.y * 64;
    int tid = threadIdx.x;
    int sr = tid >> 2;
    int sk = (tid & 3) * 8;
    int lane = tid & 63;
    int wid = tid >> 6;
    int wm = (wid & 1) * 32, wn = (wid >> 1) * 32;
    int l15 = lane & 15, lk = (lane >> 4) * 8;

    short8v ra_h = *(const short8v*)&Ahi[(size_t)(m0+sr)*512 + sk];
    short8v ra_l = *(const short8v*)&Alo[(size_t)(m0+sr)*512 + sk];
    short8v rb_h = *(const short8v*)&Bhi[(size_t)(n0+sr)*512 + sk];
    short8v rb_l = *(const short8v*)&Blo[(size_t)(n0+sr)*512 + sk];
    f32x4 acc[2][2] = {{{0.f,0.f,0.f,0.f},{0.f,0.f,0.f,0.f}},
                       {{0.f,0.f,0.f,0.f},{0.f,0.f,0.f,0.f}}};
    for (int k0 = 0; k0 < 512; k0 += 32){
        __syncthreads();
        *(short8v*)&Ah[sr][sk] = ra_h;
        *(short8v*)&Al[sr][sk] = ra_l;
        *(short8v*)&Bh[sr][sk] = rb_h;
        *(short8v*)&Bl[sr][sk] = rb_l;
        __syncthreads();
        if (k0 + 32 < 512){
            ra_h = *(const short8v*)&Ahi[(size_t)(m0+sr)*512 + k0+32 + sk];
            ra_l = *(const short8v*)&Alo[(size_t)(m0+sr)*512 + k0+32 + sk];
            rb_h = *(const short8v*)&Bhi[(size_t)(n0+sr)*512 + k0+32 + sk];
            rb_l = *(const short8v*)&Blo[(size_t)(n0+sr)*512 + k0+32 + sk];
        }
        short8v ah0 = *(const short8v*)&Ah[wm +  0 + l15][lk];
        short8v ah1 = *(const short8v*)&Ah[wm + 16 + l15][lk];
        short8v al0 = *(const short8v*)&Al[wm +  0 + l15][lk];
        short8v al1 = *(const short8v*)&Al[wm + 16 + l15][lk];
        short8v bh0 = *(const short8v*)&Bh[wn +  0 + l15][lk];
        short8v bh1 = *(const short8v*)&Bh[wn + 16 + l15][lk];
        short8v bl0 = *(const short8v*)&Bl[wn +  0 + l15][lk];
        short8v bl1 = *(const short8v*)&Bl[wn + 16 + l15][lk];
        acc[0][0] = __builtin_amdgcn_mfma_f32_16x16x32_bf16(ah0, bh0, acc[0][0], 0, 0, 0);
        acc[0][0] = __builtin_amdgcn_mfma_f32_16x16x32_bf16(ah0, bl0, acc[0][0], 0, 0, 0);
        acc[0][0] = __builtin_amdgcn_mfma_f32_16x16x32_bf16(al0, bh0, acc[0][0], 0, 0, 0);
        acc[0][1] = __builtin_amdgcn_mfma_f32_16x16x32_bf16(ah0, bh1, acc[0][1], 0, 0, 0);
        acc[0][1] = __builtin_amdgcn_mfma_f32_16x16x32_bf16(ah0, bl1, acc[0][1], 0, 0, 0);
        acc[0][1] = __builtin_amdgcn_mfma_f32_16x16x32_bf16(al0, bh1, acc[0][1], 0, 0, 0);
        acc[1][0] = __builtin_amdgcn_mfma_f32_16x16x32_bf16(ah1, bh0, acc[1][0], 0, 0, 0);
        acc[1][0] = __builtin_amdgcn_mfma_f32_16x16x32_bf16(ah1, bl0, acc[1][0], 0, 0, 0);
        acc[1][0] = __builtin_amdgcn_mfma_f32_16x16x32_bf16(al1, bh0, acc[1][0], 0, 0, 0);
        acc[1][1] = __builtin_amdgcn_mfma_f32_16x16x32_bf16(ah1, bh1, acc[1][1], 0, 0, 0);
        acc[1][1] = __builtin_amdgcn_mfma_f32_16x16x32_bf16(ah1, bl1, acc[1][1], 0, 0, 0);
        acc[1][1] = __builtin_amdgcn_mfma_f32_16x16x32_bf16(al1, bh1, acc[1][1], 0, 0, 0);
    }
    int colbase = n0 + wn + l15;
    float bo0 = bo[colbase], bo1 = bo[colbase + 16];
    int r4 = (lane >> 4) * 4;
#pragma unroll
    for (int mf = 0; mf < 2; ++mf){
#pragma unroll
        for (int r = 0; r < 4; ++r){
            int row = m0 + wm + mf*16 + r4 + r;
            float v0 = acc[mf][0][r] + bo0;
            float v1 = acc[mf][1][r] + bo1;
            float* crow = Cout + (size_t)row * (NSTEP * (size_t)V_);
            crow[colbase] = v0;
            crow[colbase + 16] = v1;
            unsigned long long pk0 = ((unsigned long long)fkey(v0) << 32) | (unsigned)(4095 - colbase);
            unsigned long long pk1 = ((unsigned long long)fkey(v1) << 32) | (unsigned)(4095 - (colbase+16));
            unsigned long long best = pk0 > pk1 ? pk0 : pk1;
#pragma unroll
            for (int off = 1; off < 16; off <<= 1){
                unsigned long long o = __shfl_xor(best, off);
                if (o > best) best = o;
            }
            if (l15 == 0) atomicMax(&Pcur[row], best);
        }
    }
}

__global__ __launch_bounds__(256) void final_pred(const unsigned long long* __restrict__ P,
                                                  float* __restrict__ preds){
    int b = threadIdx.x;
    int w = 4095 - (int)(P[b] & 0xFFFFFFFFull);
    if (w < 0) w = 0; if (w > 4095) w = 4095;
    preds[b*NSTEP + (NSTEP-1)] = (float)w;
}

extern "C" void kernel_launch(void* const* d_in, const int* in_sizes, int n_in,
                              void* d_out, int out_size, void* d_ws, size_t ws_size,
                              hipStream_t stream){
    const float* elhs = (const float*)d_in[0];
    const float* enc  = (const float*)d_in[1];
    const float* emb  = (const float*)d_in[3];
    const float* W1   = (const float*)d_in[4];
    const float* W2   = (const float*)d_in[6];
    const float* W3   = (const float*)d_in[8];
    const float* W4   = (const float*)d_in[10];
    const float* Ww   = (const float*)d_in[12];
    const float* Wih  = (const float*)d_in[13];
    const float* bih  = (const float*)d_in[14];
    const float* Whh  = (const float*)d_in[15];
    const float* bhh  = (const float*)d_in[16];
    const float* Wo   = (const float*)d_in[17];
    const float* bo   = (const float*)d_in[18];

    float* out = (float*)d_out;
    float* preds = out + (size_t)B_ * NSTEP * V_;

    float* ws = (float*)d_ws;
    float* Eproj  = ws;  ws += (size_t)V_ * 1536;
    float* gictx  = ws;  ws += (size_t)B_ * 1536;
    float* ctx    = ws;  ws += B_ * H_;
    float* scores = ws;  ws += B_ * S_;
    float* t1     = ws;  ws += 512;
    float* t2     = ws;  ws += 512;
    float* weff   = ws;  ws += 512;
    float* Hbuf0  = ws;  ws += B_ * H_;
    float* Hbuf1  = ws;  ws += B_ * H_;
    unsigned long long* P = (unsigned long long*)ws;  ws += 1024;  // 512 u64
    unsigned short* WoT_hi = (unsigned short*)ws;  ws += (size_t)V_ * 512 / 2;
    unsigned short* WoT_lo = (unsigned short*)ws;  ws += (size_t)V_ * 512 / 2;
    unsigned short* hn_hi  = (unsigned short*)ws;  ws += B_ * H_ / 2;
    unsigned short* hn_lo  = (unsigned short*)ws;  ws += B_ * H_ / 2;

    // collapse attention MLP: weff = W1@W2@W3@W4@Ww (first 512 rows of W1)
    matvec512<<<512, 64, 0, stream>>>(W4, Ww, t1);
    matvec512<<<512, 64, 0, stream>>>(W3, t1, t2);
    matvec512<<<512, 64, 0, stream>>>(W2, t2, t1);
    matvec512<<<512, 64, 0, stream>>>(W1, t1, weff);
    score_kernel<<<(B_*S_)/4, 256, 0, stream>>>(enc, weff, scores);
    softmax_ctx<<<B_, 512, 0, stream>>>(enc, scores, ctx);
    {   // gi_ctx = ctx @ W_ih[:,1024:]^T + b_ih
        dim3 g(B_/32, 1536/64);
        gemm_abt<32><<<g, 256, 0, stream>>>(ctx, 512, Wih + 1024, 1536, bih, gictx, 1536, 512);
    }
    {   // E_proj = embedding @ W_ih[:,0:1024]^T  (f32, VALU-bound c[8][8])
        dim3 g(V_/128, 1536/128);
        gemm128<<<g, 256, 0, stream>>>(emb, 1024, Wih, 1536, Eproj, 1536, 1024);
    }
    {   // Wo -> transposed bf16 hi/lo
        dim3 g(512/64, V_/64);
        wo_split<<<g, 256, 0, stream>>>(Wo, WoT_hi, WoT_lo);
    }

    for (int t = 0; t < NSTEP; ++t){
        const float* hin = (t == 0) ? elhs : ((t & 1) ? Hbuf0 : Hbuf1);
        float* hout = (t & 1) ? Hbuf1 : Hbuf0;
        const unsigned long long* Pprev = (t == 0) ? nullptr : P + ((t-1) & 1) * B_;
        unsigned long long* Pcur = P + (t & 1) * B_;
        dim3 gs(B_/32, 512/16);
        step_hidden<<<gs, 256, 0, stream>>>(hin, hout, hn_hi, hn_lo, Whh, bhh,
                                            Eproj, gictx, Pprev, Pcur, preds, t);
        dim3 gl(B_/64, V_/64);
        logits_mfma<<<gl, 256, 0, stream>>>(hn_hi, hn_lo, WoT_hi, WoT_lo, bo,
                                            out + (size_t)t * V_, Pcur);
    }
    final_pred<<<1, 256, 0, stream>>>(P, preds);
}

// Round 3
// 1047.842 us; speedup vs baseline: 1.7292x; 1.5798x over previous
//
#include <hip/hip_runtime.h>

#define B_ 256
#define S_ 80
#define H_ 512
#define WD_ 1024
#define V_ 4096
#define NSTEP 27

typedef unsigned short u16;
typedef __attribute__((ext_vector_type(8))) short short8v;
typedef __attribute__((ext_vector_type(4))) float f32x4;
typedef __attribute__((ext_vector_type(4))) unsigned short ushort4v;

// monotonic key for f32 (order-preserving as unsigned)
__device__ __forceinline__ unsigned fkey(float v){
    unsigned u = __float_as_uint(v);
    return (u & 0x80000000u) ? ~u : (u | 0x80000000u);
}

__device__ __forceinline__ u16 bf16_rne(float f){
    unsigned u = __float_as_uint(f);
    unsigned r = (u + 0x7FFFu + ((u >> 16) & 1u)) >> 16;
    return (u16)r;
}

// float4 -> bf16 hi/lo splits
__device__ __forceinline__ void split_f4(float4 v, ushort4v& hi, ushort4v& lo){
    float arr[4] = {v.x, v.y, v.z, v.w};
    ushort4v h, l;
#pragma unroll
    for (int i = 0; i < 4; ++i){
        u16 hb = bf16_rne(arr[i]);
        float hf = __uint_as_float(((unsigned)hb) << 16);
        h[i] = hb;
        l[i] = bf16_rne(arr[i] - hf);
    }
    hi = h; lo = l;
}

// ---------- front (h-independent attention) ----------
__global__ __launch_bounds__(64) void matvec512(const float* __restrict__ W,
                                                const float* __restrict__ v,
                                                float* __restrict__ out){
    int row = blockIdx.x;
    int lane = threadIdx.x;
    const float* wr = W + row * 512;
    float s = 0.f;
#pragma unroll
    for (int i = 0; i < 8; ++i) s += wr[lane + 64*i] * v[lane + 64*i];
#pragma unroll
    for (int off = 32; off; off >>= 1) s += __shfl_xor(s, off);
    if (lane == 0) out[row] = s;
}

__global__ __launch_bounds__(256) void score_kernel(const float* __restrict__ enc,
                                                    const float* __restrict__ weff,
                                                    float* __restrict__ scores){
    int wv = threadIdx.x >> 6, lane = threadIdx.x & 63;
    int p = blockIdx.x * 4 + wv;
    const float* e = enc + (size_t)p * 512;
    float s = 0.f;
#pragma unroll
    for (int i = 0; i < 8; ++i) s += e[lane + 64*i] * weff[lane + 64*i];
#pragma unroll
    for (int off = 32; off; off >>= 1) s += __shfl_xor(s, off);
    if (lane == 0) scores[p] = s;
}

__global__ __launch_bounds__(512) void softmax_ctx(const float* __restrict__ enc,
                                                   const float* __restrict__ scores,
                                                   float* __restrict__ ctx){
    __shared__ float att[S_];
    int b = blockIdx.x, tid = threadIdx.x;
    if (tid < S_) att[tid] = scores[b*S_ + tid];
    __syncthreads();
    if (tid == 0){
        float mx = att[0];
        for (int s = 1; s < S_; ++s) mx = fmaxf(mx, att[s]);
        float sum = 0.f;
        for (int s = 0; s < S_; ++s){ float e = expf(att[s] - mx); att[s] = e; sum += e; }
        float inv = 1.f / sum;
        for (int s = 0; s < S_; ++s) att[s] *= inv;
    }
    __syncthreads();
    float a = 0.f;
    const float* eb = enc + (size_t)b * (S_*H_);
    for (int s = 0; s < S_; ++s) a += att[s] * eb[s*H_ + tid];
    ctx[b*H_ + tid] = a;
}

// small f32 GEMM for gictx: C[m,n] = sum_k A[m,k]*Bm[n,k] + bias
template<int TM>
__global__ __launch_bounds__(256) void gemm_abt(const float* __restrict__ A, int lda,
                                                const float* __restrict__ Bm, int ldb,
                                                const float* __restrict__ bias,
                                                float* __restrict__ C, int ldc,
                                                int K){
    constexpr int RPT = TM / 16;
    __shared__ float As[16][TM + 4];
    __shared__ float Bs[16][64 + 4];
    int m0 = blockIdx.x * TM, n0 = blockIdx.y * 64;
    int tid = threadIdx.x;
    int lk = tid & 15, lr = tid >> 4;
    int tx = tid & 15, ty = tid >> 4;
    float c[RPT][4] = {};
    for (int k0 = 0; k0 < K; k0 += 16){
#pragma unroll
        for (int i = 0; i < RPT; ++i)
            As[lk][lr*RPT + i] = A[(size_t)(m0 + lr*RPT + i)*lda + k0 + lk];
#pragma unroll
        for (int i = 0; i < 4; ++i)
            Bs[lk][lr*4 + i] = Bm[(size_t)(n0 + lr*4 + i)*ldb + k0 + lk];
        __syncthreads();
#pragma unroll
        for (int k = 0; k < 16; ++k){
            float b4[4];
            *(float4*)b4 = *(const float4*)&Bs[k][tx*4];
#pragma unroll
            for (int i = 0; i < RPT; ++i){
                float a = As[k][ty*RPT + i];
#pragma unroll
                for (int j = 0; j < 4; ++j) c[i][j] += a * b4[j];
            }
        }
        __syncthreads();
    }
#pragma unroll
    for (int j = 0; j < 4; ++j){
        float bb = bias ? bias[n0 + tx*4 + j] : 0.f;
#pragma unroll
        for (int i = 0; i < RPT; ++i)
            C[(size_t)(m0 + ty*RPT + i)*ldc + n0 + tx*4 + j] = c[i][j] + bb;
    }
}

// generic f32 -> bf16 hi/lo split (flat, float4 per thread)
__global__ __launch_bounds__(256) void split_mat(const float* __restrict__ src,
                                                 u16* __restrict__ hi,
                                                 u16* __restrict__ lo){
    int idx = (blockIdx.x * 256 + threadIdx.x) * 4;
    float4 v = *(const float4*)&src[idx];
    ushort4v h, l; split_f4(v, h, l);
    *(ushort4v*)&hi[idx] = h;
    *(ushort4v*)&lo[idx] = l;
}

// Wo (512x4096, k-major) -> transposed bf16 splits WoT_hi/lo (4096x512, n-major)
__global__ __launch_bounds__(256) void wo_split(const float* __restrict__ Wo,
                                                u16* __restrict__ Thi,
                                                u16* __restrict__ Tlo){
    __shared__ float T[64][65];
    int k0 = blockIdx.x * 64, n0 = blockIdx.y * 64;
    int tid = threadIdx.x;
#pragma unroll
    for (int i = 0; i < 16; ++i){
        int idx = tid + i*256;
        int kk = idx >> 6, nn = idx & 63;
        T[kk][nn] = Wo[(size_t)(k0+kk)*4096 + n0+nn];
    }
    __syncthreads();
#pragma unroll
    for (int i = 0; i < 16; ++i){
        int idx = tid + i*256;
        int nn = idx >> 6, kk = idx & 63;
        float v = T[kk][nn];
        u16 hi = bf16_rne(v);
        float hf = __uint_as_float(((unsigned)hi) << 16);
        u16 lo = bf16_rne(v - hf);
        size_t o = (size_t)(n0+nn)*512 + k0+kk;
        Thi[o] = hi; Tlo[o] = lo;
    }
}

// Eproj = emb(4096x1024) @ WihL^T(1536x1024) via split-bf16 MFMA, on-the-fly split.
// Tile 64x64, 4 waves (2x2 of 32x32). grid (24 n, 64 m).
__global__ __launch_bounds__(256) void eproj_mfma(const float* __restrict__ A,
                                                  const float* __restrict__ B,
                                                  float* __restrict__ C){
    __shared__ u16 Ah[64][40], Al[64][40], Bh[64][40], Bl[64][40];
    int n0 = blockIdx.x * 64, m0 = blockIdx.y * 64;
    int tid = threadIdx.x, lane = tid & 63, wid = tid >> 6;
    int wm = (wid & 1) * 32, wn = (wid >> 1) * 32;
    int l15 = lane & 15, lk = (lane >> 4) * 8;
    int sr = tid >> 2, sk = (tid & 3) * 8;
    f32x4 acc[2][2] = {};
    const float* arow = A + (size_t)(m0+sr)*1024;
    const float* brow = B + (size_t)(n0+sr)*1536;
    float4 a0 = *(const float4*)&arow[sk], a1 = *(const float4*)&arow[sk+4];
    float4 b0 = *(const float4*)&brow[sk], b1 = *(const float4*)&brow[sk+4];
    for (int k0 = 0; k0 < 1024; k0 += 32){
        __syncthreads();
        ushort4v h, l;
        split_f4(a0, h, l); *(ushort4v*)&Ah[sr][sk] = h;   *(ushort4v*)&Al[sr][sk] = l;
        split_f4(a1, h, l); *(ushort4v*)&Ah[sr][sk+4] = h; *(ushort4v*)&Al[sr][sk+4] = l;
        split_f4(b0, h, l); *(ushort4v*)&Bh[sr][sk] = h;   *(ushort4v*)&Bl[sr][sk] = l;
        split_f4(b1, h, l); *(ushort4v*)&Bh[sr][sk+4] = h; *(ushort4v*)&Bl[sr][sk+4] = l;
        __syncthreads();
        if (k0 + 32 < 1024){
            a0 = *(const float4*)&arow[k0+32+sk]; a1 = *(const float4*)&arow[k0+32+sk+4];
            b0 = *(const float4*)&brow[k0+32+sk]; b1 = *(const float4*)&brow[k0+32+sk+4];
        }
        short8v ah0 = *(const short8v*)&Ah[wm +  0 + l15][lk];
        short8v ah1 = *(const short8v*)&Ah[wm + 16 + l15][lk];
        short8v al0 = *(const short8v*)&Al[wm +  0 + l15][lk];
        short8v al1 = *(const short8v*)&Al[wm + 16 + l15][lk];
        short8v bh0 = *(const short8v*)&Bh[wn +  0 + l15][lk];
        short8v bh1 = *(const short8v*)&Bh[wn + 16 + l15][lk];
        short8v bl0 = *(const short8v*)&Bl[wn +  0 + l15][lk];
        short8v bl1 = *(const short8v*)&Bl[wn + 16 + l15][lk];
        acc[0][0] = __builtin_amdgcn_mfma_f32_16x16x32_bf16(ah0, bh0, acc[0][0], 0, 0, 0);
        acc[0][0] = __builtin_amdgcn_mfma_f32_16x16x32_bf16(ah0, bl0, acc[0][0], 0, 0, 0);
        acc[0][0] = __builtin_amdgcn_mfma_f32_16x16x32_bf16(al0, bh0, acc[0][0], 0, 0, 0);
        acc[0][1] = __builtin_amdgcn_mfma_f32_16x16x32_bf16(ah0, bh1, acc[0][1], 0, 0, 0);
        acc[0][1] = __builtin_amdgcn_mfma_f32_16x16x32_bf16(ah0, bl1, acc[0][1], 0, 0, 0);
        acc[0][1] = __builtin_amdgcn_mfma_f32_16x16x32_bf16(al0, bh1, acc[0][1], 0, 0, 0);
        acc[1][0] = __builtin_amdgcn_mfma_f32_16x16x32_bf16(ah1, bh0, acc[1][0], 0, 0, 0);
        acc[1][0] = __builtin_amdgcn_mfma_f32_16x16x32_bf16(ah1, bl0, acc[1][0], 0, 0, 0);
        acc[1][0] = __builtin_amdgcn_mfma_f32_16x16x32_bf16(al1, bh0, acc[1][0], 0, 0, 0);
        acc[1][1] = __builtin_amdgcn_mfma_f32_16x16x32_bf16(ah1, bh1, acc[1][1], 0, 0, 0);
        acc[1][1] = __builtin_amdgcn_mfma_f32_16x16x32_bf16(ah1, bl1, acc[1][1], 0, 0, 0);
        acc[1][1] = __builtin_amdgcn_mfma_f32_16x16x32_bf16(al1, bh1, acc[1][1], 0, 0, 0);
    }
    int col0 = n0 + wn + l15;
    int rg = lane >> 4;
#pragma unroll
    for (int mf = 0; mf < 2; ++mf){
#pragma unroll
        for (int r = 0; r < 4; ++r){
            int row = m0 + wm + mf*16 + rg*4 + r;
            C[(size_t)row*1536 + col0]      = acc[mf][0][r];
            C[(size_t)row*1536 + col0 + 16] = acc[mf][1][r];
        }
    }
}

// Per-step: gh = h@Whh^T (MFMA, pre-split Whh) fused with GRU pointwise + decode.
// Block tile: 32 rows x 32 j (all 3 gates). 4 waves: 16x16 each. grid (8, 16).
__global__ __launch_bounds__(256) void step_gru(
    const float* __restrict__ h_in, float* __restrict__ h_out,
    const u16* __restrict__ WhhHi, const u16* __restrict__ WhhLo,
    const float* __restrict__ bhh,
    const float* __restrict__ Eproj, const float* __restrict__ gictx,
    const unsigned long long* __restrict__ Pprev,
    unsigned long long* __restrict__ Pcur,
    float* __restrict__ preds, int t){
    __shared__ u16 Ah[32][40], Al[32][40];
    __shared__ u16 Bh[96][40], Bl[96][40];
    __shared__ int widx[32];
    int m0 = blockIdx.x * 32, j0 = blockIdx.y * 32;
    int tid = threadIdx.x;
    if (blockIdx.x == 0 && blockIdx.y == 0) Pcur[tid] = 0ULL;
    if (tid < 32){
        int b = m0 + tid;
        int w = 1;
        if (t > 0){
            w = 4095 - (int)(Pprev[b] & 0xFFFFFFFFull);
            if (w < 0) w = 0; if (w > 4095) w = 4095;
            if (blockIdx.y == 0) preds[b*NSTEP + (t-1)] = (float)w;
        }
        widx[tid] = w;
    }
    int arow = tid >> 3, ak = (tid & 7) * 4;
    int lane = tid & 63, wid = tid >> 6;
    int wm = (wid & 1) * 16, wj = (wid >> 1) * 16;
    int l15 = lane & 15, lk = (lane >> 4) * 8;
    f32x4 acc[3] = {};

    float4 aR = *(const float4*)&h_in[(size_t)(m0+arow)*512 + ak];
    short8v bR[3];
#pragma unroll
    for (int i = 0; i < 3; ++i){
        int c = tid + i*256;
        int s = (c >= 384); int cc = c - s*384;
        int r = cc >> 2, k8 = (cc & 3) * 8;
        int grow = (r >> 5)*512 + j0 + (r & 31);
        const u16* src = s ? WhhLo : WhhHi;
        bR[i] = *(const short8v*)&src[(size_t)grow*512 + k8];
    }
    for (int k0 = 0; k0 < 512; k0 += 32){
        __syncthreads();
        ushort4v h4, l4; split_f4(aR, h4, l4);
        *(ushort4v*)&Ah[arow][ak] = h4;
        *(ushort4v*)&Al[arow][ak] = l4;
#pragma unroll
        for (int i = 0; i < 3; ++i){
            int c = tid + i*256;
            int s = (c >= 384); int cc = c - s*384;
            int r = cc >> 2, k8 = (cc & 3) * 8;
            if (s) *(short8v*)&Bl[r][k8] = bR[i];
            else   *(short8v*)&Bh[r][k8] = bR[i];
        }
        __syncthreads();
        if (k0 + 32 < 512){
            aR = *(const float4*)&h_in[(size_t)(m0+arow)*512 + k0+32 + ak];
#pragma unroll
            for (int i = 0; i < 3; ++i){
                int c = tid + i*256;
                int s = (c >= 384); int cc = c - s*384;
                int r = cc >> 2, k8 = (cc & 3) * 8;
                int grow = (r >> 5)*512 + j0 + (r & 31);
                const u16* src = s ? WhhLo : WhhHi;
                bR[i] = *(const short8v*)&src[(size_t)grow*512 + k0+32 + k8];
            }
        }
        short8v ah = *(const short8v*)&Ah[wm + l15][lk];
        short8v al = *(const short8v*)&Al[wm + l15][lk];
#pragma unroll
        for (int g = 0; g < 3; ++g){
            short8v bh = *(const short8v*)&Bh[g*32 + wj + l15][lk];
            short8v bl = *(const short8v*)&Bl[g*32 + wj + l15][lk];
            acc[g] = __builtin_amdgcn_mfma_f32_16x16x32_bf16(ah, bh, acc[g], 0, 0, 0);
            acc[g] = __builtin_amdgcn_mfma_f32_16x16x32_bf16(ah, bl, acc[g], 0, 0, 0);
            acc[g] = __builtin_amdgcn_mfma_f32_16x16x32_bf16(al, bh, acc[g], 0, 0, 0);
        }
    }
    int jg = j0 + wj + l15;
    float br_ = bhh[jg], bz_ = bhh[512 + jg], bn_ = bhh[1024 + jg];
    int rg = lane >> 4;
#pragma unroll
    for (int r = 0; r < 4; ++r){
        int rl = wm + rg*4 + r;
        int row = m0 + rl;
        int w = widx[rl];
        const float* ep = Eproj + (size_t)w * 1536;
        const float* gc = gictx + (size_t)row * 1536;
        float gir = ep[jg]        + gc[jg]        + acc[0][r] + br_;
        float giz = ep[512 + jg]  + gc[512 + jg]  + acc[1][r] + bz_;
        float gin = ep[1024 + jg] + gc[1024 + jg];
        float rr = 1.f / (1.f + expf(-gir));
        float zz = 1.f / (1.f + expf(-giz));
        float nn = tanhf(gin + rr * (acc[2][r] + bn_));
        float hold = h_in[(size_t)row*512 + jg];
        h_out[(size_t)row*512 + jg] = (1.f - zz)*nn + zz*hold;
    }
}

// logits = hn @ Wo + bo via split-bf16 MFMA (A split on-the-fly), fused argmax.
// Tile 32 rows x 64 cols, 4 waves (16x32 each). grid (64 n, 8 m).
__global__ __launch_bounds__(256) void logits_mfma2(
    const float* __restrict__ A,
    const u16* __restrict__ Bhi, const u16* __restrict__ Blo,
    const float* __restrict__ bo, float* __restrict__ Cout,
    unsigned long long* __restrict__ Pcur){
    __shared__ u16 Ah[32][40], Al[32][40];
    __shared__ u16 Bh[64][40], Bl[64][40];
    int n0 = blockIdx.x * 64, m0 = blockIdx.y * 32;
    int tid = threadIdx.x, lane = tid & 63, wid = tid >> 6;
    int wm = (wid & 1) * 16, wn = (wid >> 1) * 32;
    int l15 = lane & 15, lk = (lane >> 4) * 8;
    int arow = tid >> 3, ak = (tid & 7) * 4;
    int bn = tid >> 2, bk8 = (tid & 3) * 8;
    f32x4 acc[2] = {};
    float4 aR = *(const float4*)&A[(size_t)(m0+arow)*512 + ak];
    short8v bhR = *(const short8v*)&Bhi[(size_t)(n0+bn)*512 + bk8];
    short8v blR = *(const short8v*)&Blo[(size_t)(n0+bn)*512 + bk8];
    for (int k0 = 0; k0 < 512; k0 += 32){
        __syncthreads();
        ushort4v h4, l4; split_f4(aR, h4, l4);
        *(ushort4v*)&Ah[arow][ak] = h4;
        *(ushort4v*)&Al[arow][ak] = l4;
        *(short8v*)&Bh[bn][bk8] = bhR;
        *(short8v*)&Bl[bn][bk8] = blR;
        __syncthreads();
        if (k0 + 32 < 512){
            aR = *(const float4*)&A[(size_t)(m0+arow)*512 + k0+32 + ak];
            bhR = *(const short8v*)&Bhi[(size_t)(n0+bn)*512 + k0+32 + bk8];
            blR = *(const short8v*)&Blo[(size_t)(n0+bn)*512 + k0+32 + bk8];
        }
        short8v ah = *(const short8v*)&Ah[wm + l15][lk];
        short8v al = *(const short8v*)&Al[wm + l15][lk];
#pragma unroll
        for (int q = 0; q < 2; ++q){
            short8v bh = *(const short8v*)&Bh[wn + q*16 + l15][lk];
            short8v bl = *(const short8v*)&Bl[wn + q*16 + l15][lk];
            acc[q] = __builtin_amdgcn_mfma_f32_16x16x32_bf16(ah, bh, acc[q], 0, 0, 0);
            acc[q] = __builtin_amdgcn_mfma_f32_16x16x32_bf16(ah, bl, acc[q], 0, 0, 0);
            acc[q] = __builtin_amdgcn_mfma_f32_16x16x32_bf16(al, bh, acc[q], 0, 0, 0);
        }
    }
    int col0 = n0 + wn + l15;
    float bo0 = bo[col0], bo1 = bo[col0 + 16];
    int rg = lane >> 4;
#pragma unroll
    for (int r = 0; r < 4; ++r){
        int row = m0 + wm + rg*4 + r;
        float v0 = acc[0][r] + bo0;
        float v1 = acc[1][r] + bo1;
        float* crow = Cout + (size_t)row * (NSTEP * (size_t)V_);
        crow[col0]      = v0;
        crow[col0 + 16] = v1;
        unsigned long long pk0 = ((unsigned long long)fkey(v0) << 32) | (unsigned)(4095 - col0);
        unsigned long long pk1 = ((unsigned long long)fkey(v1) << 32) | (unsigned)(4095 - (col0+16));
        unsigned long long best = pk0 > pk1 ? pk0 : pk1;
#pragma unroll
        for (int off = 1; off < 16; off <<= 1){
            unsigned long long o = __shfl_xor(best, off);
            if (o > best) best = o;
        }
        if (l15 == 0) atomicMax(&Pcur[row], best);
    }
}

__global__ __launch_bounds__(256) void final_pred(const unsigned long long* __restrict__ P,
                                                  float* __restrict__ preds){
    int b = threadIdx.x;
    int w = 4095 - (int)(P[b] & 0xFFFFFFFFull);
    if (w < 0) w = 0; if (w > 4095) w = 4095;
    preds[b*NSTEP + (NSTEP-1)] = (float)w;
}

extern "C" void kernel_launch(void* const* d_in, const int* in_sizes, int n_in,
                              void* d_out, int out_size, void* d_ws, size_t ws_size,
                              hipStream_t stream){
    const float* elhs = (const float*)d_in[0];
    const float* enc  = (const float*)d_in[1];
    const float* emb  = (const float*)d_in[3];
    const float* W1   = (const float*)d_in[4];
    const float* W2   = (const float*)d_in[6];
    const float* W3   = (const float*)d_in[8];
    const float* W4   = (const float*)d_in[10];
    const float* Ww   = (const float*)d_in[12];
    const float* Wih  = (const float*)d_in[13];
    const float* bih  = (const float*)d_in[14];
    const float* Whh  = (const float*)d_in[15];
    const float* bhh  = (const float*)d_in[16];
    const float* Wo   = (const float*)d_in[17];
    const float* bo   = (const float*)d_in[18];

    float* out = (float*)d_out;
    float* preds = out + (size_t)B_ * NSTEP * V_;

    float* ws = (float*)d_ws;
    float* Eproj  = ws;  ws += (size_t)V_ * 1536;
    float* gictx  = ws;  ws += (size_t)B_ * 1536;
    float* ctx    = ws;  ws += B_ * H_;
    float* scores = ws;  ws += B_ * S_;
    float* t1     = ws;  ws += 512;
    float* t2     = ws;  ws += 512;
    float* weff   = ws;  ws += 512;
    float* Hbuf0  = ws;  ws += B_ * H_;
    float* Hbuf1  = ws;  ws += B_ * H_;
    unsigned long long* P = (unsigned long long*)ws;  ws += 1024;
    u16* WoT_hi = (u16*)ws;  ws += (size_t)V_ * 512 / 2;
    u16* WoT_lo = (u16*)ws;  ws += (size_t)V_ * 512 / 2;
    u16* WhhHi  = (u16*)ws;  ws += 1536 * 512 / 2;
    u16* WhhLo  = (u16*)ws;  ws += 1536 * 512 / 2;

    // one-time weight transforms (independent of front chain)
    split_mat<<<1536*512/(4*256), 256, 0, stream>>>(Whh, WhhHi, WhhLo);
    {
        dim3 g(512/64, V_/64);
        wo_split<<<g, 256, 0, stream>>>(Wo, WoT_hi, WoT_lo);
    }

    // collapse attention MLP: weff = W1@W2@W3@W4@Ww (first 512 rows of W1)
    matvec512<<<512, 64, 0, stream>>>(W4, Ww, t1);
    matvec512<<<512, 64, 0, stream>>>(W3, t1, t2);
    matvec512<<<512, 64, 0, stream>>>(W2, t2, t1);
    matvec512<<<512, 64, 0, stream>>>(W1, t1, weff);
    score_kernel<<<(B_*S_)/4, 256, 0, stream>>>(enc, weff, scores);
    softmax_ctx<<<B_, 512, 0, stream>>>(enc, scores, ctx);
    {   // gi_ctx = ctx @ W_ih[:,1024:]^T + b_ih
        dim3 g(B_/32, 1536/64);
        gemm_abt<32><<<g, 256, 0, stream>>>(ctx, 512, Wih + 1024, 1536, bih, gictx, 1536, 512);
    }
    {   // E_proj = embedding @ W_ih[:,0:1024]^T  (split-bf16 MFMA)
        dim3 g(1536/64, V_/64);
        eproj_mfma<<<g, 256, 0, stream>>>(emb, Wih, Eproj);
    }

    for (int t = 0; t < NSTEP; ++t){
        const float* hin = (t == 0) ? elhs : ((t & 1) ? Hbuf0 : Hbuf1);
        float* hout = (t & 1) ? Hbuf1 : Hbuf0;
        const unsigned long long* Pprev = (t == 0) ? nullptr : P + ((t-1) & 1) * B_;
        unsigned long long* Pcur = P + (t & 1) * B_;
        dim3 gs(B_/32, 512/32);
        step_gru<<<gs, 256, 0, stream>>>(hin, hout, WhhHi, WhhLo, bhh,
                                         Eproj, gictx, Pprev, Pcur, preds, t);
        dim3 gl(V_/64, B_/32);
        logits_mfma2<<<gl, 256, 0, stream>>>(hout, WoT_hi, WoT_lo, bo,
                                             out + (size_t)t * V_, Pcur);
    }
    final_pred<<<1, 256, 0, stream>>>(P, preds);
}